// Round 1
// baseline (141.423 us; speedup 1.0000x reference)
//
#include <hip/hip_runtime.h>

// Problem constants (fixed by setup_inputs): B=16, N=3000, M=300, L=80, K=4
#define BB 16
#define NN 3000
#define MM 300
#define KK 4
#define IOU_THRESH 0.6f

struct Box { float x1, y1, x2, y2, area; };

__device__ __forceinline__ Box to_xyxy(float4 b) {
#pragma clang fp contract(off)
    Box r;
    r.x1 = b.x - 0.5f * b.z;
    r.y1 = b.y - 0.5f * b.w;
    r.x2 = b.x + 0.5f * b.z;
    r.y2 = b.y + 0.5f * b.w;
    r.area = (r.x2 - r.x1) * (r.y2 - r.y1);
    return r;
}

// a = gt box, b = proposal box (matches ref arg order; all ops commutative anyway)
__device__ __forceinline__ float pair_iou(Box a, Box b) {
#pragma clang fp contract(off)
    float ltx = fmaxf(a.x1, b.x1);
    float lty = fmaxf(a.y1, b.y1);
    float rbx = fminf(a.x2, b.x2);
    float rby = fminf(a.y2, b.y2);
    float wx = fmaxf(rbx - ltx, 0.0f);
    float wy = fmaxf(rby - lty, 0.0f);
    float inter = wx * wy;
    float uni = a.area + b.area - inter;
    return inter / fmaxf(uni, 1e-9f);
}

// monotonic float -> u32 mapping (total order matches float order; only finite vals here)
__device__ __forceinline__ unsigned int f32_to_ordered(float f) {
    unsigned int u = __float_as_uint(f);
    return (u & 0x80000000u) ? ~u : (u | 0x80000000u);
}
__device__ __forceinline__ float ordered_to_f32(unsigned int u) {
    unsigned int b = (u & 0x80000000u) ? (u & 0x7FFFFFFFu) : ~u;
    return __uint_as_float(b);
}

// Kernel A: one block per (b, m). Computes top-4 of masked-IoU row m (ties -> smaller n,
// exactly lax.top_k semantics), gmax[b][m] = row max, and zeroes counts.
__global__ __launch_bounds__(256) void kA(const float4* __restrict__ props,
                                          const int*    __restrict__ pinds,
                                          const int*    __restrict__ glab,
                                          const float4* __restrict__ gbox,
                                          float* __restrict__ topv,
                                          int*   __restrict__ topi,
                                          float* __restrict__ gmaxv,
                                          int*   __restrict__ counts) {
    int m = blockIdx.x, b = blockIdx.y;
    int bm = b * MM + m;
    Box gb = to_xyxy(gbox[bm]);
    int gl = glab[bm];
    const float4* pp = props + (size_t)b * NN;
    const int*    pi = pinds + (size_t)b * NN;

    unsigned long long k0 = 0, k1 = 0, k2 = 0, k3 = 0;
    for (int n = threadIdx.x; n < NN; n += 256) {
        float4 p = pp[n];
        Box pb = to_xyxy(p);
        float iou = pair_iou(gb, pb);
        float v = (pi[n] == gl) ? iou : -1.0f;
        unsigned long long key =
            ((unsigned long long)f32_to_ordered(v) << 32) |
            (unsigned long long)(0xFFFFFFFFu - (unsigned int)n);
        if (key > k3) {
            if (key > k0)      { k3 = k2; k2 = k1; k1 = k0; k0 = key; }
            else if (key > k1) { k3 = k2; k2 = k1; k1 = key; }
            else if (key > k2) { k3 = k2; k2 = key; }
            else               { k3 = key; }
        }
    }

    __shared__ unsigned long long red[4];
    for (int r = 0; r < KK; ++r) {
        unsigned long long v = k0;
        #pragma unroll
        for (int off = 32; off > 0; off >>= 1) {
            unsigned long long o = __shfl_down(v, (unsigned)off, 64);
            v = (v > o) ? v : o;
        }
        if ((threadIdx.x & 63) == 0) red[threadIdx.x >> 6] = v;
        __syncthreads();
        if (threadIdx.x == 0) {
            unsigned long long w = red[0];
            #pragma unroll
            for (int i = 1; i < 4; ++i) w = (w > red[i]) ? w : red[i];
            red[0] = w;
        }
        __syncthreads();
        unsigned long long w = red[0];
        __syncthreads();  // protect red[] reuse next round
        if (k0 == w) { k0 = k1; k1 = k2; k2 = k3; k3 = 0; }  // unique keys: one popper
        if (threadIdx.x == 0) {
            float val = ordered_to_f32((unsigned int)(w >> 32));
            int   idx = (int)(0xFFFFFFFFu - (unsigned int)w);
            topv[bm * KK + r] = val;
            topi[bm * KK + r] = idx;
            if (r == 0) gmaxv[bm] = val;
        }
    }
    if (threadIdx.x == 0) counts[bm] = 0;
}

// Kernel B: one thread per (b, n). best_iou/best_gt (first-occurrence argmax),
// lq via exact equality vs gmax, pos -> atomicAdd counts[best_gt].
__global__ __launch_bounds__(256) void kB(const float4* __restrict__ props,
                                          const int*    __restrict__ pinds,
                                          const int*    __restrict__ glab,
                                          const float4* __restrict__ gbox,
                                          const float*  __restrict__ gmaxv,
                                          int* __restrict__ counts) {
    int b = blockIdx.y;
    int n = blockIdx.x * 256 + threadIdx.x;

    __shared__ float sx1[MM], sy1[MM], sx2[MM], sy2[MM], sar[MM], sgm[MM];
    __shared__ int   slab[MM];
    for (int i = threadIdx.x; i < MM; i += 256) {
        Box g = to_xyxy(gbox[b * MM + i]);
        sx1[i] = g.x1; sy1[i] = g.y1; sx2[i] = g.x2; sy2[i] = g.y2; sar[i] = g.area;
        slab[i] = glab[b * MM + i];
        sgm[i]  = gmaxv[b * MM + i];
    }
    __syncthreads();

    if (n < NN) {
        Box pb = to_xyxy(props[(size_t)b * NN + n]);
        int pi = pinds[(size_t)b * NN + n];
        float best = -1.0f;
        int bestm = 0;
        bool lq = false;
        for (int m = 0; m < MM; ++m) {
            Box a; a.x1 = sx1[m]; a.y1 = sy1[m]; a.x2 = sx2[m]; a.y2 = sy2[m]; a.area = sar[m];
            float iou = pair_iou(a, pb);
            bool mt = (slab[m] == pi);
            float v = mt ? iou : -1.0f;
            if (v > best) { best = v; bestm = m; }   // strict > = first-occurrence argmax
            lq |= (mt && (iou == sgm[m]));
        }
        bool valid_prop = (best >= 0.0f);
        bool pos = valid_prop && ((best >= IOU_THRESH) || lq);
        if (pos) atomicAdd(&counts[b * MM + bestm], 1);
    }
}

// Kernel C: epilogue. One thread per (b,m); writes 4 output chunks as float32.
__global__ __launch_bounds__(256) void kC(const float* __restrict__ topv,
                                          const int*   __restrict__ topi,
                                          const int*   __restrict__ counts,
                                          float* __restrict__ out) {
    int i = blockIdx.x * 256 + threadIdx.x;  // i in [0, B*M)
    if (i >= BB * MM) return;
    const int CH = BB * MM * KK;  // 19200 elems per output chunk
    int m = i % MM;
    int take = min(counts[i], KK);
    #pragma unroll
    for (int j = 0; j < KK; ++j) {
        bool v = (j < take);
        float tv = topv[i * KK + j];
        int   ti = topi[i * KK + j];
        out[0 * CH + i * KK + j] = v ? (float)ti : -1.0f;   // rows
        out[1 * CH + i * KK + j] = v ? (float)m  : -1.0f;   // cols
        out[2 * CH + i * KK + j] = v ? 1.0f : 0.0f;         // valid
        out[3 * CH + i * KK + j] = v ? tv : 0.0f;           // sel_iou
    }
}

extern "C" void kernel_launch(void* const* d_in, const int* in_sizes, int n_in,
                              void* d_out, int out_size, void* d_ws, size_t ws_size,
                              hipStream_t stream) {
    // inputs: 0 pred_logits_match (unused), 1 pred_boxes (unused),
    //         2 init_reference (proposals), 3 prompt_inds, 4 gt_labels,
    //         5 gt_boxes, 6 max_k (==4, hardcoded)
    const float4* props = (const float4*)d_in[2];
    const int*    pinds = (const int*)d_in[3];
    const int*    glab  = (const int*)d_in[4];
    const float4* gbox  = (const float4*)d_in[5];
    float* out = (float*)d_out;

    // workspace layout (192 KB total)
    float* topv   = (float*)d_ws;                 // B*M*K
    int*   topi   = (int*)(topv + BB * MM * KK);  // B*M*K
    float* gmaxv  = (float*)(topi + BB * MM * KK);// B*M
    int*   counts = (int*)(gmaxv + BB * MM);      // B*M

    dim3 gA(MM, BB);
    kA<<<gA, 256, 0, stream>>>(props, pinds, glab, gbox, topv, topi, gmaxv, counts);
    dim3 gB((NN + 255) / 256, BB);
    kB<<<gB, 256, 0, stream>>>(props, pinds, glab, gbox, gmaxv, counts);
    kC<<<(BB * MM + 255) / 256, 256, 0, stream>>>(topv, topi, counts, out);
}

// Round 2
// 123.844 us; speedup vs baseline: 1.1419x; 1.1419x over previous
//
#include <hip/hip_runtime.h>

// Problem constants (fixed by setup_inputs): B=16, N=3000, M=300, L=80, K=4
#define BB 16
#define NN 3000
#define MM 300
#define KK 4
#define IOU_THRESH 0.6f

typedef unsigned long long u64;

struct Box { float x1, y1, x2, y2, area; };

__device__ __forceinline__ Box to_xyxy(float4 b) {
#pragma clang fp contract(off)
    Box r;
    r.x1 = b.x - 0.5f * b.z;
    r.y1 = b.y - 0.5f * b.w;
    r.x2 = b.x + 0.5f * b.z;
    r.y2 = b.y + 0.5f * b.w;
    r.area = (r.x2 - r.x1) * (r.y2 - r.y1);
    return r;
}

// Must be bitwise-identical between kA and kB (iou == gmax equality depends on it).
__device__ __forceinline__ float pair_iou(Box a, Box b) {
#pragma clang fp contract(off)
    float ltx = fmaxf(a.x1, b.x1);
    float lty = fmaxf(a.y1, b.y1);
    float rbx = fminf(a.x2, b.x2);
    float rby = fminf(a.y2, b.y2);
    float wx = fmaxf(rbx - ltx, 0.0f);
    float wy = fmaxf(rby - lty, 0.0f);
    float inter = wx * wy;
    float uni = a.area + b.area - inter;
    return inter / fmaxf(uni, 1e-9f);
}

// monotonic float <-> u32 (order-preserving bijection, finite values)
__device__ __forceinline__ unsigned int f32_to_ordered(float f) {
    unsigned int u = __float_as_uint(f);
    return (u & 0x80000000u) ? ~u : (u | 0x80000000u);
}
__device__ __forceinline__ float ordered_to_f32(unsigned int u) {
    unsigned int b = (u & 0x80000000u) ? (u & 0x7FFFFFFFu) : ~u;
    return __uint_as_float(b);
}

__device__ __forceinline__ u64 umax64(u64 a, u64 b) { return a > b ? a : b; }
__device__ __forceinline__ u64 umin64(u64 a, u64 b) { return a < b ? a : b; }

__device__ __forceinline__ u64 shfl_xor_u64(u64 v, int mask) {
    int lo = __shfl_xor((int)(unsigned)v, mask, 64);
    int hi = __shfl_xor((int)(unsigned)(v >> 32), mask, 64);
    return ((u64)(unsigned)hi << 32) | (u64)(unsigned)lo;
}

// branchless insert of k into sorted-desc 4-list
__device__ __forceinline__ void topins(u64 t[4], u64 k) {
    u64 c0 = umin64(t[0], k);
    t[0] = umax64(t[0], k);
    u64 c1 = umin64(t[1], c0);
    t[1] = umax64(t[1], c0);
    u64 c2 = umin64(t[2], c1);
    t[2] = umax64(t[2], c1);
    t[3] = umax64(t[3], c2);
}

// butterfly: top-4 of the union of all 64 lanes' sorted-desc 4-lists (all lanes get result)
__device__ __forceinline__ void wave_merge_top4(u64 t[4]) {
    #pragma unroll
    for (int s = 1; s < 64; s <<= 1) {
        u64 b0 = shfl_xor_u64(t[0], s);
        u64 b1 = shfl_xor_u64(t[1], s);
        u64 b2 = shfl_xor_u64(t[2], s);
        u64 b3 = shfl_xor_u64(t[3], s);
        u64 a0 = t[0], a1 = t[1], a2 = t[2], a3 = t[3];
        // merged top-4 of two sorted-desc 4-lists
        t[0] = umax64(a0, b0);
        t[1] = umax64(umin64(a0, b0), umax64(a1, b1));
        t[2] = umax64(umax64(a2, b2), umax64(umin64(a0, b1), umin64(a1, b0)));
        t[3] = umax64(umax64(a3, b3),
               umax64(umin64(a0, b2), umax64(umin64(a1, b1), umin64(a2, b0))));
    }
}

// Kernel A: grid (ceil(MM/8), B), block 256 = 4 waves; wave handles GT rows m0=bx*8+2w, m0+1.
// Produces topv/topi (exact lax.top_k order), packed GT struct (box+area+gmax+label) for kB,
// and zeroes counts. No block barriers.
__global__ __launch_bounds__(256) void kA(const float4* __restrict__ props,
                                          const int*    __restrict__ pinds,
                                          const int*    __restrict__ glab,
                                          const float4* __restrict__ gbox,
                                          float*  __restrict__ topv,
                                          int*    __restrict__ topi,
                                          float4* __restrict__ gtp,
                                          int*    __restrict__ counts) {
    int b = blockIdx.y;
    int wv = __builtin_amdgcn_readfirstlane((int)(threadIdx.x >> 6));
    int lane = threadIdx.x & 63;
    int m0 = blockIdx.x * 8 + wv * 2;
    if (m0 >= MM) return;
    int m1 = m0 + 1;          // MM even, m0 even -> always valid
    int bm0 = b * MM + m0, bm1 = bm0 + 1;

    Box g0 = to_xyxy(gbox[bm0]);
    Box g1 = to_xyxy(gbox[bm1]);
    int l0 = glab[bm0], l1 = glab[bm1];

    const float4* pp = props + (size_t)b * NN;
    const int*    pi = pinds + (size_t)b * NN;

    u64 t0[4] = {0, 0, 0, 0};
    u64 t1[4] = {0, 0, 0, 0};
    #pragma unroll 2
    for (int n = lane; n < NN; n += 64) {
        float4 p = pp[n];
        int lbl = pi[n];
        Box pb = to_xyxy(p);
        float i0 = pair_iou(g0, pb);
        float i1 = pair_iou(g1, pb);
        float v0 = (lbl == l0) ? i0 : -1.0f;
        float v1 = (lbl == l1) ? i1 : -1.0f;
        u64 nk = (u64)(0xFFFFFFFFu - (unsigned)n);
        topins(t0, ((u64)f32_to_ordered(v0) << 32) | nk);
        topins(t1, ((u64)f32_to_ordered(v1) << 32) | nk);
    }
    wave_merge_top4(t0);
    wave_merge_top4(t1);

    if (lane == 0) {
        float gm0 = ordered_to_f32((unsigned)(t0[0] >> 32));
        float gm1 = ordered_to_f32((unsigned)(t1[0] >> 32));
        #pragma unroll
        for (int j = 0; j < KK; ++j) {
            topv[bm0 * KK + j] = ordered_to_f32((unsigned)(t0[j] >> 32));
            topi[bm0 * KK + j] = (int)(0xFFFFFFFFu - (unsigned)t0[j]);
            topv[bm1 * KK + j] = ordered_to_f32((unsigned)(t1[j] >> 32));
            topi[bm1 * KK + j] = (int)(0xFFFFFFFFu - (unsigned)t1[j]);
        }
        gtp[bm0 * 2 + 0] = make_float4(g0.x1, g0.y1, g0.x2, g0.y2);
        gtp[bm0 * 2 + 1] = make_float4(g0.area, gm0, __int_as_float(l0), 0.0f);
        gtp[bm1 * 2 + 0] = make_float4(g1.x1, g1.y1, g1.x2, g1.y2);
        gtp[bm1 * 2 + 1] = make_float4(g1.area, gm1, __int_as_float(l1), 0.0f);
        counts[bm0] = 0;
        counts[bm1] = 0;
    }
}

// Kernel B: grid (ceil(NN/64), B), block 256 = 4 waves. Block covers 64 proposals;
// wave w scans m in [75w, 75w+75) with wave-uniform (scalar) GT loads. Partial
// argmax keys + lq flags combined via LDS; wave 0 emits atomicAdd into counts.
__global__ __launch_bounds__(256) void kB(const float4* __restrict__ props,
                                          const int*    __restrict__ pinds,
                                          const float4* __restrict__ gtp,
                                          int* __restrict__ counts) {
    int b = blockIdx.y;
    int wv = __builtin_amdgcn_readfirstlane((int)(threadIdx.x >> 6));
    int lane = threadIdx.x & 63;
    int p = blockIdx.x * 64 + lane;
    bool pv = (p < NN);
    int psafe = pv ? p : (NN - 1);

    float4 pr = props[(size_t)b * NN + psafe];
    int lbl = pv ? pinds[(size_t)b * NN + psafe] : -1;
    Box pb = to_xyxy(pr);

    const float4* gp = gtp + ((size_t)b * MM + (size_t)wv * 75) * 2;
    int mbase = wv * 75;

    u64 key = 0;
    bool lq = false;
    #pragma unroll 5
    for (int j = 0; j < 75; ++j) {
        float4 q0 = gp[2 * j];       // wave-uniform -> scalar loads
        float4 q1 = gp[2 * j + 1];
        Box a;
        a.x1 = q0.x; a.y1 = q0.y; a.x2 = q0.z; a.y2 = q0.w;
        a.area = q1.x;
        float gm = q1.y;
        int gl = __float_as_int(q1.z);
        float iou = pair_iou(a, pb);
        bool mt = (gl == lbl);
        float v = mt ? iou : -1.0f;
        u64 k = ((u64)f32_to_ordered(v) << 32) |
                (u64)(0xFFFFFFFFu - (unsigned)(mbase + j));
        key = umax64(key, k);
        lq = lq || (mt && (iou == gm));
    }

    __shared__ u64 sk[4][64];
    __shared__ int sl[4][64];
    sk[wv][lane] = key;
    sl[wv][lane] = lq ? 1 : 0;
    __syncthreads();

    if (threadIdx.x < 64) {
        u64 k = umax64(umax64(sk[0][lane], sk[1][lane]),
                       umax64(sk[2][lane], sk[3][lane]));
        int l = sl[0][lane] | sl[1][lane] | sl[2][lane] | sl[3][lane];
        float v = ordered_to_f32((unsigned)(k >> 32));
        int bestm = (int)(0xFFFFFFFFu - (unsigned)k);
        bool pos = pv && (v >= 0.0f) && ((v >= IOU_THRESH) || (l != 0));
        if (pos) atomicAdd(&counts[b * MM + bestm], 1);
    }
}

// Kernel C: epilogue, one thread per (b,m); float4 writes per output chunk.
__global__ __launch_bounds__(256) void kC(const float* __restrict__ topv,
                                          const int*   __restrict__ topi,
                                          const int*   __restrict__ counts,
                                          float* __restrict__ out) {
    int i = blockIdx.x * 256 + threadIdx.x;  // [0, B*M)
    if (i >= BB * MM) return;
    int m = i % MM;
    int take = min(counts[i], KK);
    float4 tv = ((const float4*)topv)[i];
    int4   ti = ((const int4*)topi)[i];
    float4 rows, cols, valid, sel;
    rows.x = (0 < take) ? (float)ti.x : -1.0f;
    rows.y = (1 < take) ? (float)ti.y : -1.0f;
    rows.z = (2 < take) ? (float)ti.z : -1.0f;
    rows.w = (3 < take) ? (float)ti.w : -1.0f;
    cols.x = (0 < take) ? (float)m : -1.0f;
    cols.y = (1 < take) ? (float)m : -1.0f;
    cols.z = (2 < take) ? (float)m : -1.0f;
    cols.w = (3 < take) ? (float)m : -1.0f;
    valid.x = (0 < take) ? 1.0f : 0.0f;
    valid.y = (1 < take) ? 1.0f : 0.0f;
    valid.z = (2 < take) ? 1.0f : 0.0f;
    valid.w = (3 < take) ? 1.0f : 0.0f;
    sel.x = (0 < take) ? tv.x : 0.0f;
    sel.y = (1 < take) ? tv.y : 0.0f;
    sel.z = (2 < take) ? tv.z : 0.0f;
    sel.w = (3 < take) ? tv.w : 0.0f;
    float4* o = (float4*)out;
    const int CH4 = BB * MM;  // 4800 float4s per chunk
    o[0 * CH4 + i] = rows;
    o[1 * CH4 + i] = cols;
    o[2 * CH4 + i] = valid;
    o[3 * CH4 + i] = sel;
}

extern "C" void kernel_launch(void* const* d_in, const int* in_sizes, int n_in,
                              void* d_out, int out_size, void* d_ws, size_t ws_size,
                              hipStream_t stream) {
    // inputs: 0 pred_logits_match (unused), 1 pred_boxes (unused),
    //         2 init_reference (proposals), 3 prompt_inds, 4 gt_labels,
    //         5 gt_boxes, 6 max_k (==4, hardcoded)
    const float4* props = (const float4*)d_in[2];
    const int*    pinds = (const int*)d_in[3];
    const int*    glab  = (const int*)d_in[4];
    const float4* gbox  = (const float4*)d_in[5];
    float* out = (float*)d_out;

    // ws layout (172.8 KB, within proven budget):
    float* topv   = (float*)d_ws;                  // B*M*K floats (76.8 KB)
    int*   topi   = (int*)(topv + BB * MM * KK);   // B*M*K ints  (76.8 KB)
    int*   counts = (int*)(topi + BB * MM * KK);   // B*M ints    (19.2 KB)
    // packed GT scratch (B*M*2 float4 = 153.6 KB) lives in d_out (307 KB);
    // kA writes -> kB reads -> kC overwrites d_out. Stream-ordered, safe.
    float4* gtp = (float4*)d_out;

    dim3 gA((MM + 7) / 8, BB);
    kA<<<gA, 256, 0, stream>>>(props, pinds, glab, gbox, topv, topi, gtp, counts);
    dim3 gB((NN + 63) / 64, BB);
    kB<<<gB, 256, 0, stream>>>(props, pinds, gtp, counts);
    kC<<<(BB * MM + 255) / 256, 256, 0, stream>>>(topv, topi, counts, out);
}

// Round 3
// 90.153 us; speedup vs baseline: 1.5687x; 1.3737x over previous
//
#include <hip/hip_runtime.h>

// Problem constants (fixed by setup_inputs): B=16, N=3000, M=300, L=80, K=4
#define BB 16
#define NN 3000
#define MM 300
#define LL 80
#define KK 4
#define IOU_THRESH 0.6f

typedef unsigned long long u64;

struct Box { float x1, y1, x2, y2, area; };

__device__ __forceinline__ Box to_xyxy(float4 b) {
#pragma clang fp contract(off)
    Box r;
    r.x1 = b.x - 0.5f * b.z;
    r.y1 = b.y - 0.5f * b.w;
    r.x2 = b.x + 0.5f * b.z;
    r.y2 = b.y + 0.5f * b.w;
    r.area = (r.x2 - r.x1) * (r.y2 - r.y1);
    return r;
}

// Must be bitwise-identical between kTop and kAsn (iou == gmax equality depends on it).
__device__ __forceinline__ float pair_iou(Box a, Box b) {
#pragma clang fp contract(off)
    float ltx = fmaxf(a.x1, b.x1);
    float lty = fmaxf(a.y1, b.y1);
    float rbx = fminf(a.x2, b.x2);
    float rby = fminf(a.y2, b.y2);
    float wx = fmaxf(rbx - ltx, 0.0f);
    float wy = fmaxf(rby - lty, 0.0f);
    float inter = wx * wy;
    float uni = a.area + b.area - inter;
    return inter / fmaxf(uni, 1e-9f);
}

// monotonic float <-> u32 (order-preserving bijection, finite values)
__device__ __forceinline__ unsigned int f32_to_ordered(float f) {
    unsigned int u = __float_as_uint(f);
    return (u & 0x80000000u) ? ~u : (u | 0x80000000u);
}
__device__ __forceinline__ float ordered_to_f32(unsigned int u) {
    unsigned int b = (u & 0x80000000u) ? (u & 0x7FFFFFFFu) : ~u;
    return __uint_as_float(b);
}

__device__ __forceinline__ u64 umax64(u64 a, u64 b) { return a > b ? a : b; }
__device__ __forceinline__ u64 umin64(u64 a, u64 b) { return a < b ? a : b; }

__device__ __forceinline__ u64 shfl_xor_u64(u64 v, int mask) {
    int lo = __shfl_xor((int)(unsigned)v, mask, 64);
    int hi = __shfl_xor((int)(unsigned)(v >> 32), mask, 64);
    return ((u64)(unsigned)hi << 32) | (u64)(unsigned)lo;
}

// branchless insert of k into sorted-desc 4-list
__device__ __forceinline__ void topins(u64 t[4], u64 k) {
    u64 c0 = umin64(t[0], k);
    t[0] = umax64(t[0], k);
    u64 c1 = umin64(t[1], c0);
    t[1] = umax64(t[1], c0);
    u64 c2 = umin64(t[2], c1);
    t[2] = umax64(t[2], c1);
    t[3] = umax64(t[3], c2);
}

// butterfly: top-4 of the union of all 64 lanes' sorted-desc 4-lists (all lanes get result)
__device__ __forceinline__ void wave_merge_top4(u64 t[4]) {
    #pragma unroll
    for (int s = 1; s < 64; s <<= 1) {
        u64 b0 = shfl_xor_u64(t[0], s);
        u64 b1 = shfl_xor_u64(t[1], s);
        u64 b2 = shfl_xor_u64(t[2], s);
        u64 b3 = shfl_xor_u64(t[3], s);
        u64 a0 = t[0], a1 = t[1], a2 = t[2], a3 = t[3];
        t[0] = umax64(a0, b0);
        t[1] = umax64(umin64(a0, b0), umax64(a1, b1));
        t[2] = umax64(umax64(a2, b2), umax64(umin64(a0, b1), umin64(a1, b0)));
        t[3] = umax64(umax64(a3, b3),
               umax64(umin64(a0, b2), umax64(umin64(a1, b1), umin64(a2, b0))));
    }
}

// ---------------------------------------------------------------------------
// kBin: one block per batch. Label-histogram + exclusive prefix + scatter of
// proposal indices (ushort) and GT row indices (ushort) into per-label buckets.
// Also zeroes counts. Bucket order is nondeterministic (LDS atomic cursors) but
// all downstream results are order-invariant (u64 key max / OR / int adds).
__global__ __launch_bounds__(256) void kBin(const int* __restrict__ pinds,
                                            const int* __restrict__ glab,
                                            unsigned short* __restrict__ pidx,
                                            int* __restrict__ pstart,
                                            int* __restrict__ pcnt,
                                            unsigned short* __restrict__ gidx,
                                            int* __restrict__ gstart,
                                            int* __restrict__ gcnt,
                                            int* __restrict__ counts) {
    int b = blockIdx.x;
    int tid = threadIdx.x;
    __shared__ int hist[LL], cur[LL], gh[LL], gcur[LL];
    if (tid < LL) { hist[tid] = 0; gh[tid] = 0; }
    __syncthreads();
    for (int n = tid; n < NN; n += 256) atomicAdd(&hist[pinds[b * NN + n]], 1);
    for (int m = tid; m < MM; m += 256) atomicAdd(&gh[glab[b * MM + m]], 1);
    __syncthreads();
    if (tid < LL) {
        int s = 0;
        for (int j = 0; j < tid; ++j) s += hist[j];
        cur[tid] = s; pstart[b * LL + tid] = s; pcnt[b * LL + tid] = hist[tid];
        int t = 0;
        for (int j = 0; j < tid; ++j) t += gh[j];
        gcur[tid] = t; gstart[b * LL + tid] = t; gcnt[b * LL + tid] = gh[tid];
    }
    __syncthreads();
    for (int n = tid; n < NN; n += 256) {
        int l = pinds[b * NN + n];
        int pos = atomicAdd(&cur[l], 1);
        pidx[b * NN + pos] = (unsigned short)n;
    }
    for (int m = tid; m < MM; m += 256) {
        int l = glab[b * MM + m];
        int pos = atomicAdd(&gcur[l], 1);
        gidx[b * MM + pos] = (unsigned short)m;
    }
    for (int i = tid; i < MM; i += 256) counts[b * MM + i] = 0;
}

// ---------------------------------------------------------------------------
// kTop: one wave per GT bucket position. Scans only the proposal bucket of the
// row's label (~37 entries). Writes exact lax.top_k(v,idx) top-4 (slots beyond
// the match count are padding, always masked by kC since take<=match_count),
// gmax, and a packed GT record (box+area+gmax+m) in bucket order for kAsn.
// d_out layout: floats [0,38400) GT records | [38400,57600) topv | [57600,76800) topi
__global__ __launch_bounds__(256) void kTop(const float4* __restrict__ props,
                                            const int*    __restrict__ glab,
                                            const float4* __restrict__ gbox,
                                            const unsigned short* __restrict__ pidx,
                                            const int* __restrict__ pstart,
                                            const int* __restrict__ pcnt,
                                            const unsigned short* __restrict__ gidx,
                                            float* out) {
    int b = blockIdx.y;
    int wv = __builtin_amdgcn_readfirstlane((int)(threadIdx.x >> 6));
    int lane = threadIdx.x & 63;
    int g = blockIdx.x * 4 + wv;            // grid.x = 75 -> g in [0,300)
    int m = gidx[b * MM + g];
    int bm = b * MM + m;
    Box gt = to_xyxy(gbox[bm]);
    int l = glab[bm];
    int s = pstart[b * LL + l], c = pcnt[b * LL + l];

    const u64 init = ((u64)f32_to_ordered(-1.0f) << 32);
    u64 t[4] = {init, init, init, init};
    for (int i = lane; i < c; i += 64) {   // c ~ 37, usually a single pass
        int n = pidx[b * NN + s + i];
        Box pb = to_xyxy(props[(size_t)b * NN + n]);
        float iou = pair_iou(gt, pb);      // all bucket entries match -> v = iou
        u64 key = ((u64)f32_to_ordered(iou) << 32) |
                  (u64)(0xFFFFFFFFu - (unsigned)n);
        topins(t, key);
    }
    wave_merge_top4(t);

    if (lane == 0) {
        float gm = ordered_to_f32((unsigned)(t[0] >> 32));
        float* topv = out + 2 * KK * BB * MM / KK * KK;  // = out + 38400
        int*   topi = (int*)(out + 3 * BB * MM * KK / 1);// placeholder, fixed below
        topv = out + 2 * BB * MM * KK / 2;               // keep simple:
        topv = out + 38400;
        topi = (int*)(out + 57600);
        #pragma unroll
        for (int j = 0; j < KK; ++j) {
            topv[bm * KK + j] = ordered_to_f32((unsigned)(t[j] >> 32));
            topi[bm * KK + j] = (int)(0xFFFFFFFFu - (unsigned)t[j]);
        }
        float4* gtb = (float4*)out;
        int gpos = b * MM + g;
        gtb[gpos * 2 + 0] = make_float4(gt.x1, gt.y1, gt.x2, gt.y2);
        gtb[gpos * 2 + 1] = make_float4(gt.area, gm, __int_as_float(m), 0.0f);
    }
}

// ---------------------------------------------------------------------------
// kAsn: one thread per proposal. Scans only the GT bucket of its label
// (~3.75 rows): best_gt via u64 key (first-occurrence argmax = min-m tie-break),
// lq via exact bitwise iou==gmax, then one atomicAdd into counts.
__global__ __launch_bounds__(256) void kAsn(const float4* __restrict__ props,
                                            const int*    __restrict__ pinds,
                                            const int* __restrict__ gstart,
                                            const int* __restrict__ gcnt,
                                            const float* __restrict__ out,
                                            int* __restrict__ counts) {
    int b = blockIdx.y;
    int n = blockIdx.x * 256 + threadIdx.x;
    if (n >= NN) return;
    float4 pr = props[(size_t)b * NN + n];
    int lbl = pinds[(size_t)b * NN + n];
    Box pb = to_xyxy(pr);
    int s = gstart[b * LL + lbl], c = gcnt[b * LL + lbl];
    const float4* gtb = (const float4*)out;

    u64 key = 0;
    bool lq = false;
    for (int j = 0; j < c; ++j) {
        int idx = (b * MM + s + j) * 2;
        float4 q0 = gtb[idx], q1 = gtb[idx + 1];
        Box a; a.x1 = q0.x; a.y1 = q0.y; a.x2 = q0.z; a.y2 = q0.w; a.area = q1.x;
        float iou = pair_iou(a, pb);
        int m = __float_as_int(q1.z);
        u64 k = ((u64)f32_to_ordered(iou) << 32) |
                (u64)(0xFFFFFFFFu - (unsigned)m);
        key = umax64(key, k);
        lq = lq || (iou == q1.y);
    }
    if (c > 0) {  // valid_prop; all scanned pairs match so best v >= 0
        float v = ordered_to_f32((unsigned)(key >> 32));
        int bm = (int)(0xFFFFFFFFu - (unsigned)key);
        if ((v >= IOU_THRESH) || lq) atomicAdd(&counts[b * MM + bm], 1);
    }
}

// ---------------------------------------------------------------------------
// kC: epilogue. Thread i reads topv/topi (back half of d_out) and counts, then
// writes the 4 output chunks. Overlapping slots (chunk2==topv, chunk3==topi
// regions) are read-before-write within the same thread; GT-record region
// (chunks 0-1) is dead after kAsn.
__global__ __launch_bounds__(256) void kC(const int* __restrict__ counts,
                                          float* out) {
    int i = blockIdx.x * 256 + threadIdx.x;  // [0, B*M)
    if (i >= BB * MM) return;
    int m = i % MM;
    int take = min(counts[i], KK);
    float4 tv = ((const float4*)(out + 38400))[i];
    int4   ti = ((const int4*)(out + 57600))[i];
    float4 rows, cols, valid, sel;
    rows.x = (0 < take) ? (float)ti.x : -1.0f;
    rows.y = (1 < take) ? (float)ti.y : -1.0f;
    rows.z = (2 < take) ? (float)ti.z : -1.0f;
    rows.w = (3 < take) ? (float)ti.w : -1.0f;
    cols.x = (0 < take) ? (float)m : -1.0f;
    cols.y = (1 < take) ? (float)m : -1.0f;
    cols.z = (2 < take) ? (float)m : -1.0f;
    cols.w = (3 < take) ? (float)m : -1.0f;
    valid.x = (0 < take) ? 1.0f : 0.0f;
    valid.y = (1 < take) ? 1.0f : 0.0f;
    valid.z = (2 < take) ? 1.0f : 0.0f;
    valid.w = (3 < take) ? 1.0f : 0.0f;
    sel.x = (0 < take) ? tv.x : 0.0f;
    sel.y = (1 < take) ? tv.y : 0.0f;
    sel.z = (2 < take) ? tv.z : 0.0f;
    sel.w = (3 < take) ? tv.w : 0.0f;
    float4* o = (float4*)out;
    const int CH4 = BB * MM;  // 4800 float4s per chunk
    o[0 * CH4 + i] = rows;
    o[1 * CH4 + i] = cols;
    o[2 * CH4 + i] = valid;
    o[3 * CH4 + i] = sel;
}

extern "C" void kernel_launch(void* const* d_in, const int* in_sizes, int n_in,
                              void* d_out, int out_size, void* d_ws, size_t ws_size,
                              hipStream_t stream) {
    // inputs: 0 pred_logits_match (unused), 1 pred_boxes (unused),
    //         2 init_reference (proposals), 3 prompt_inds, 4 gt_labels,
    //         5 gt_boxes, 6 max_k (==4, hardcoded)
    const float4* props = (const float4*)d_in[2];
    const int*    pinds = (const int*)d_in[3];
    const int*    glab  = (const int*)d_in[4];
    const float4* gbox  = (const float4*)d_in[5];
    float* out = (float*)d_out;

    // ws layout (145.3 KB total, within proven budget):
    char* w = (char*)d_ws;
    int*   counts = (int*)w;                 w += BB * MM * sizeof(int);      // 19200
    int*   pstart = (int*)w;                 w += BB * LL * sizeof(int);      //  5120
    int*   pcnt   = (int*)w;                 w += BB * LL * sizeof(int);      //  5120
    int*   gstart = (int*)w;                 w += BB * LL * sizeof(int);      //  5120
    int*   gcnt   = (int*)w;                 w += BB * LL * sizeof(int);      //  5120
    unsigned short* pidx = (unsigned short*)w; w += BB * NN * sizeof(short);  // 96000
    unsigned short* gidx = (unsigned short*)w;                                //  9600

    kBin<<<BB, 256, 0, stream>>>(pinds, glab, pidx, pstart, pcnt,
                                 gidx, gstart, gcnt, counts);
    dim3 gT(MM / 4, BB);  // 75 x 16, 4 waves/block, one wave per GT bucket slot
    kTop<<<gT, 256, 0, stream>>>(props, glab, gbox, pidx, pstart, pcnt, gidx, out);
    dim3 gA((NN + 255) / 256, BB);
    kAsn<<<gA, 256, 0, stream>>>(props, pinds, gstart, gcnt, out, counts);
    kC<<<(BB * MM + 255) / 256, 256, 0, stream>>>(counts, out);
}